// Round 9
// baseline (328.287 us; speedup 1.0000x reference)
//
#include <hip/hip_runtime.h>
#include <stdint.h>

#define NPTS 131072
#define CINC 128
#define COUTC 128
#define WDIM 512
#define K3 27

typedef float f32x4 __attribute__((ext_vector_type(4)));
typedef __bf16 bf16x8 __attribute__((ext_vector_type(8)));

#define GLOAD_LDS16(g, l) \
  __builtin_amdgcn_global_load_lds((const __attribute__((address_space(1))) void*)(g), \
                                   (__attribute__((address_space(3))) void*)(l), 16, 0, 0)

__device__ __forceinline__ unsigned short f2bf(float x){
  union { float f; uint32_t u; } v; v.f = x;
  uint32_t u = v.u;
  uint32_t r = (u + 0x7fffu + ((u >> 16) & 1u)) >> 16;
  return (unsigned short)r;
}

// styles[b*128+c] = dot(w[b], aw[c])/sqrt(512) + ab[c]; 4 dots/block, 1/wave
__global__ void k_styles_dot(const float* __restrict__ w, const float* __restrict__ aw,
                             const float* __restrict__ ab, float* __restrict__ styles){
  int wave = threadIdx.x >> 6, lane = threadIdx.x & 63;
  int blk = blockIdx.x * 4 + wave;            // 512 dots
  int b = blk >> 7, c = blk & 127;
  const float4* wr = (const float4*)(w + b * WDIM);
  const float4* ar = (const float4*)(aw + c * WDIM);
  float4 w0 = wr[lane * 2], w1 = wr[lane * 2 + 1];
  float4 a0 = ar[lane * 2], a1 = ar[lane * 2 + 1];
  float s = w0.x * a0.x + w0.y * a0.y + w0.z * a0.z + w0.w * a0.w
          + w1.x * a1.x + w1.y * a1.y + w1.z * a1.z + w1.w * a1.w;
  for (int off = 32; off > 0; off >>= 1) s += __shfl_down(s, off, 64);
  if (lane == 0) styles[blk] = s * 0.04419417382415922f + ab[c];
}

// merged snorm + dcoefs2: every block redundantly reduces styles^2 (2KB), then
// wave w computes dco2 for pair = blk*8+w; block 0 additionally writes sn[].
__global__ void k_sn_dco(const float* __restrict__ styles, const float* __restrict__ vmat,
                         const float* __restrict__ wnorm, const float* __restrict__ mag,
                         float* __restrict__ sn, float* __restrict__ dco2){
  __shared__ float red[512];
  int t = threadIdx.x;
  float s = styles[t];
  red[t] = s * s;
  __syncthreads();
  for (int off = 256; off > 0; off >>= 1){
    if (t < off) red[t] += red[t + off];
    __syncthreads();
  }
  float rs = rsqrtf(red[0] * (1.0f / 512.0f));
  if (blockIdx.x == 0) sn[t] = s * rs;
  int wave = t >> 6, lane = t & 63;
  int pair = blockIdx.x * 8 + wave;          // b*128+co
  int b = pair >> 7, co = pair & 127;
  float s0 = styles[b * 128 + lane] * rs, s1 = styles[b * 128 + 64 + lane] * rs;
  float sum = vmat[co * 128 + lane] * s0 * s0 + vmat[co * 128 + 64 + lane] * s1 * s1;
  for (int off = 32; off > 0; off >>= 1) sum += __shfl_down(sum, off, 64);
  if (lane == 0){
    float wn = wnorm[co];
    dco2[pair] = rsqrtf(sum * wn * wn + 1e-8f) * rsqrtf(mag[0]);
  }
}

// per cout: wnorm + vmat[cout][cin]=sum_k cw^2 + bpack (B-frag layout, wn-scaled)
__global__ void k_prep_w(const float* __restrict__ cw, float* __restrict__ wnorm,
                         float* __restrict__ vmat, unsigned short* __restrict__ bpack){
  __shared__ float red[128];
  int co = blockIdx.x, cin = threadIdx.x;
  const float* p = cw + co * 3456 + cin * 27;
  float r[27];
  float v = 0.f;
  #pragma unroll
  for (int k = 0; k < 27; k++){ r[k] = p[k]; v += r[k] * r[k]; }
  vmat[co * 128 + cin] = v;
  red[cin] = v;
  __syncthreads();
  for (int off = 64; off > 0; off >>= 1){
    if (cin < off) red[cin] += red[cin + off];
    __syncthreads();
  }
  float wn_s = rsqrtf(red[0] * (1.0f / 3456.0f));
  if (cin == 0) wnorm[co] = wn_s;
  int grp = co >> 4, m = co & 15;
  int kk = cin >> 5, q = (cin >> 3) & 3, j = cin & 7;
  #pragma unroll
  for (int k = 0; k < 27; k++){
    int idx = ((k * 32 + kk * 8 + grp) * 64 + q * 16 + m) * 8 + j;
    bpack[idx] = f2bf(r[k] * wn_s);
  }
}

// xpad[n][c] = bf16(x[n][c] * sn[b][c]); row NPTS = zeros
__global__ void k_xmod(const float* __restrict__ x, const float* __restrict__ sn,
                       const int* __restrict__ bidx, unsigned short* __restrict__ xpad){
  int gid = blockIdx.x * 256 + threadIdx.x;
  const int total = (NPTS + 1) * 32;
  if (gid >= total) return;
  int n = gid >> 5;
  int c4 = (gid & 31) * 4;
  unsigned short o0, o1, o2, o3;
  if (n < NPTS){
    int b = bidx[n];
    float4 xv = *(const float4*)(x + (size_t)n * CINC + c4);
    float4 sv = *(const float4*)(sn + b * CINC + c4);
    o0 = f2bf(xv.x * sv.x); o1 = f2bf(xv.y * sv.y);
    o2 = f2bf(xv.z * sv.z); o3 = f2bf(xv.w * sv.w);
  } else { o0 = o1 = o2 = o3 = 0; }
  *(ushort4*)(xpad + (size_t)n * CINC + c4) = make_ushort4(o0, o1, o2, o3);
}

__global__ void k_invinit(int* __restrict__ invT){
  int j = blockIdx.x * 256 + threadIdx.x;
  int k = blockIdx.y;
  invT[k * NPTS + j] = NPTS;
}

__global__ void k_invscat(const int* __restrict__ out_idx, const int* __restrict__ in_idx,
                          int* __restrict__ invT){
  int j = blockIdx.x * 256 + threadIdx.x;
  int k = blockIdx.y;
  int o = out_idx[k * NPTS + j];
  if (o < NPTS) invT[k * NPTS + o] = in_idx[k * NPTS + j];
}

// Main conv: block = 64 output points x 128 couts, 4 waves (2M x 2N), 256 thr.
// Counted-vmcnt pipeline (T3/T4): 4 A-buffers in LDS, gathers prefetched 2 taps
// ahead, inv indices preloaded 1 tap ahead. Per-tap vmem ISSUE ORDER (pinned by
// sched_barrier): [B_k (16, oldest) | P(k+2) gathers (4) | inv(k+3) (4, youngest)].
// One asm s_waitcnt vmcnt(8) forces B_k + all older (incl. this tap's A = P(k),
// in-order retirement) while leaving the 8 youngest (next gathers+inv) IN FLIGHT,
// then a raw s_barrier (no vmcnt(0) drain). Every gather gets a full tap of slack;
// no wait ever drains a just-issued gather -- the R0/R8 per-tap L3 stall dies.
__global__ __launch_bounds__(256, 2) void k_conv(
    const unsigned short* __restrict__ xpad,
    const unsigned short* __restrict__ bpack,
    const int* __restrict__ invT,
    const float* __restrict__ dco2,
    const float* __restrict__ cbias,
    const int* __restrict__ bidx,
    float* __restrict__ out){
  __shared__ __align__(16) unsigned short Ash[4 * 64 * 128];  // 64KB, 4 buffers
  int t = threadIdx.x;
  int wave = t >> 6, lane = t & 63;
  int wm = wave >> 1, wn = wave & 1;
  int q = lane >> 4, m16 = lane & 15;
  int base_pt = blockIdx.x * 64;
  int rbase = t >> 4, c = t & 15;      // staging: thread covers rows i*16+rbase, col c

  f32x4 acc[2][4];
  #pragma unroll
  for (int i = 0; i < 2; i++)
    #pragma unroll
    for (int j = 0; j < 4; j++) acc[i][j] = (f32x4){0.f, 0.f, 0.f, 0.f};

  auto loadIV = [&](int k, int* iv){
    const int* invk = invT + k * NPTS + base_pt;
    #pragma unroll
    for (int i = 0; i < 4; i++) iv[i] = invk[i * 16 + rbase];
  };
  auto issueP = [&](int k, const int* iv){
    unsigned short* Ab = Ash + (k & 3) * 8192;
    #pragma unroll
    for (int i = 0; i < 4; i++){
      int row = i * 16 + rbase;
      const unsigned short* src = xpad + (size_t)iv[i] * CINC + ((c ^ row) & 15) * 8;
      GLOAD_LDS16(src, Ab + (i * 256 + t) * 8);
    }
  };

  // prologue: P(0), P(1) issued (exposed once), inv(2) preloaded
  int ivP[4], ivN[4];
  loadIV(0, ivP); issueP(0, ivP);
  loadIV(1, ivP); issueP(1, ivP);
  loadIV(2, ivP);

  for (int k = 0; k < K3; k++){
    // 1) B_k loads -- oldest vmem of this tap
    bf16x8 b[4][4];
    const unsigned short* Bg = bpack + k * 16384;
    #pragma unroll
    for (int kk = 0; kk < 4; kk++)
      #pragma unroll
      for (int jn = 0; jn < 4; jn++)
        b[kk][jn] = *(const bf16x8*)(Bg + ((kk * 8 + wn * 4 + jn) * 64 + lane) * 8);
    __builtin_amdgcn_sched_barrier(0);
    // 2) prefetch A for tap k+2; preload inv for tap k+3
    if (k + 2 < K3){
      issueP(k + 2, ivP);
      if (k + 3 < K3) loadIV(k + 3, ivN);
    }
    __builtin_amdgcn_sched_barrier(0);
    // 3) counted wait + raw barrier (no drain of the in-flight gathers)
    if (k + 2 < K3) asm volatile("s_waitcnt vmcnt(8)" ::: "memory");
    else            asm volatile("s_waitcnt vmcnt(0)" ::: "memory");
    __builtin_amdgcn_sched_barrier(0);
    __builtin_amdgcn_s_barrier();
    __builtin_amdgcn_sched_barrier(0);
    // 4) MFMA on buf[k&3]
    const unsigned short* Ab = Ash + (k & 3) * 8192;
    #pragma unroll
    for (int kk = 0; kk < 4; kk++){
      int cA = ((kk * 4 + q) ^ m16) & 15;
      bf16x8 a0 = *(const bf16x8*)(Ab + (wm * 32 + m16) * 128 + cA * 8);
      bf16x8 a1 = *(const bf16x8*)(Ab + (wm * 32 + 16 + m16) * 128 + cA * 8);
      #pragma unroll
      for (int jn = 0; jn < 4; jn++){
        acc[0][jn] = __builtin_amdgcn_mfma_f32_16x16x32_bf16(a0, b[kk][jn], acc[0][jn], 0, 0, 0);
        acc[1][jn] = __builtin_amdgcn_mfma_f32_16x16x32_bf16(a1, b[kk][jn], acc[1][jn], 0, 0, 0);
      }
    }
    __builtin_amdgcn_sched_barrier(0);
    // rotate inv pipeline
    #pragma unroll
    for (int i = 0; i < 4; i++) ivP[i] = ivN[i];
  }

  // epilogue: demod + bias + leaky*sqrt2 + clip
  const float S2 = 1.41421356237309515f;
  #pragma unroll
  for (int i = 0; i < 2; i++){
    #pragma unroll
    for (int r = 0; r < 4; r++){
      int row = wm * 32 + i * 16 + q * 4 + r;   // D: row=(lane>>4)*4+reg
      int n = base_pt + row;
      int b = bidx[n];
      const float* dc = dco2 + b * COUTC;
      float* orow = out + (size_t)n * COUTC;
      #pragma unroll
      for (int jn = 0; jn < 4; jn++){
        int col = wn * 64 + jn * 16 + m16;      // D: col=lane&15
        float v = acc[i][jn][r] * dc[col] + cbias[col];
        v = (v < 0.f ? 0.2f * v : v) * S2;
        v = fminf(fmaxf(v, -256.f), 256.f);
        orow[col] = v;
      }
    }
  }
}

extern "C" void kernel_launch(void* const* d_in, const int* in_sizes, int n_in,
                              void* d_out, int out_size, void* d_ws, size_t ws_size,
                              hipStream_t stream){
  const float* x   = (const float*)d_in[0];
  const float* w   = (const float*)d_in[1];
  const float* aw  = (const float*)d_in[2];
  const float* ab  = (const float*)d_in[3];
  const float* cw  = (const float*)d_in[4];
  const float* cb  = (const float*)d_in[5];
  const float* mag = (const float*)d_in[6];
  const int* bidx    = (const int*)d_in[7];
  const int* in_idx  = (const int*)d_in[8];
  const int* out_idx = (const int*)d_in[9];
  float* out = (float*)d_out;
  char* ws = (char*)d_ws;

  float* styles = (float*)(ws + 0);         // 2048 B
  float* sn     = (float*)(ws + 2048);      // 2048 B
  float* wnorm  = (float*)(ws + 4096);      // 512 B
  float* dco2   = (float*)(ws + 4608);      // 2048 B
  float* vmat   = (float*)(ws + 8192);      // 65536 B
  unsigned short* bpack = (unsigned short*)(ws + 73728);    // 884736 B
  unsigned short* xpad  = (unsigned short*)(ws + 958464);   // 33554688 B
  int* invT     = (int*)(ws + 34513152);                    // 14155776 B -> end 48668928

  k_prep_w<<<128, 128, 0, stream>>>(cw, wnorm, vmat, bpack);
  k_styles_dot<<<128, 256, 0, stream>>>(w, aw, ab, styles);
  k_sn_dco<<<64, 512, 0, stream>>>(styles, vmat, wnorm, mag, sn, dco2);
  k_xmod<<<16385, 256, 0, stream>>>(x, sn, bidx, xpad);
  dim3 gi(512, 27);
  k_invinit<<<gi, 256, 0, stream>>>(invT);
  k_invscat<<<gi, 256, 0, stream>>>(out_idx, in_idx, invT);
  k_conv<<<2048, 256, 0, stream>>>(xpad, bpack, invT, dco2, cb, bidx, out);
}

// Round 10
// 321.296 us; speedup vs baseline: 1.0218x; 1.0218x over previous
//
#include <hip/hip_runtime.h>
#include <stdint.h>

#define NPTS 131072
#define CINC 128
#define COUTC 128
#define WDIM 512
#define K3 27

typedef float f32x4 __attribute__((ext_vector_type(4)));
typedef __bf16 bf16x8 __attribute__((ext_vector_type(8)));

#define GLOAD_LDS16(g, l) \
  __builtin_amdgcn_global_load_lds((const __attribute__((address_space(1))) void*)(g), \
                                   (__attribute__((address_space(3))) void*)(l), 16, 0, 0)

__device__ __forceinline__ unsigned short f2bf(float x){
  union { float f; uint32_t u; } v; v.f = x;
  uint32_t u = v.u;
  uint32_t r = (u + 0x7fffu + ((u >> 16) & 1u)) >> 16;
  return (unsigned short)r;
}

// styles[b*128+c] = dot(w[b], aw[c])/sqrt(512) + ab[c]; 4 dots/block, 1/wave
__global__ void k_styles_dot(const float* __restrict__ w, const float* __restrict__ aw,
                             const float* __restrict__ ab, float* __restrict__ styles){
  int wave = threadIdx.x >> 6, lane = threadIdx.x & 63;
  int blk = blockIdx.x * 4 + wave;            // 512 dots
  int b = blk >> 7, c = blk & 127;
  const float4* wr = (const float4*)(w + b * WDIM);
  const float4* ar = (const float4*)(aw + c * WDIM);
  float4 w0 = wr[lane * 2], w1 = wr[lane * 2 + 1];
  float4 a0 = ar[lane * 2], a1 = ar[lane * 2 + 1];
  float s = w0.x * a0.x + w0.y * a0.y + w0.z * a0.z + w0.w * a0.w
          + w1.x * a1.x + w1.y * a1.y + w1.z * a1.z + w1.w * a1.w;
  for (int off = 32; off > 0; off >>= 1) s += __shfl_down(s, off, 64);
  if (lane == 0) styles[blk] = s * 0.04419417382415922f + ab[c];
}

// merged snorm + dcoefs2: every block redundantly reduces styles^2 (2KB), then
// wave w computes dco2 for pair = blk*8+w; block 0 additionally writes sn[].
__global__ void k_sn_dco(const float* __restrict__ styles, const float* __restrict__ vmat,
                         const float* __restrict__ wnorm, const float* __restrict__ mag,
                         float* __restrict__ sn, float* __restrict__ dco2){
  __shared__ float red[512];
  int t = threadIdx.x;
  float s = styles[t];
  red[t] = s * s;
  __syncthreads();
  for (int off = 256; off > 0; off >>= 1){
    if (t < off) red[t] += red[t + off];
    __syncthreads();
  }
  float rs = rsqrtf(red[0] * (1.0f / 512.0f));
  if (blockIdx.x == 0) sn[t] = s * rs;
  int wave = t >> 6, lane = t & 63;
  int pair = blockIdx.x * 8 + wave;          // b*128+co
  int b = pair >> 7, co = pair & 127;
  float s0 = styles[b * 128 + lane] * rs, s1 = styles[b * 128 + 64 + lane] * rs;
  float sum = vmat[co * 128 + lane] * s0 * s0 + vmat[co * 128 + 64 + lane] * s1 * s1;
  for (int off = 32; off > 0; off >>= 1) sum += __shfl_down(sum, off, 64);
  if (lane == 0){
    float wn = wnorm[co];
    dco2[pair] = rsqrtf(sum * wn * wn + 1e-8f) * rsqrtf(mag[0]);
  }
}

// per cout: wnorm + vmat[cout][cin]=sum_k cw^2 + bpack (B-frag layout, wn-scaled)
__global__ void k_prep_w(const float* __restrict__ cw, float* __restrict__ wnorm,
                         float* __restrict__ vmat, unsigned short* __restrict__ bpack){
  __shared__ float red[128];
  int co = blockIdx.x, cin = threadIdx.x;
  const float* p = cw + co * 3456 + cin * 27;
  float r[27];
  float v = 0.f;
  #pragma unroll
  for (int k = 0; k < 27; k++){ r[k] = p[k]; v += r[k] * r[k]; }
  vmat[co * 128 + cin] = v;
  red[cin] = v;
  __syncthreads();
  for (int off = 64; off > 0; off >>= 1){
    if (cin < off) red[cin] += red[cin + off];
    __syncthreads();
  }
  float wn_s = rsqrtf(red[0] * (1.0f / 3456.0f));
  if (cin == 0) wnorm[co] = wn_s;
  int grp = co >> 4, m = co & 15;
  int kk = cin >> 5, q = (cin >> 3) & 3, j = cin & 7;
  #pragma unroll
  for (int k = 0; k < 27; k++){
    int idx = ((k * 32 + kk * 8 + grp) * 64 + q * 16 + m) * 8 + j;
    bpack[idx] = f2bf(r[k] * wn_s);
  }
}

// xpad[n][c] = bf16(x[n][c] * sn[b][c]); row NPTS = zeros
__global__ void k_xmod(const float* __restrict__ x, const float* __restrict__ sn,
                       const int* __restrict__ bidx, unsigned short* __restrict__ xpad){
  int gid = blockIdx.x * 256 + threadIdx.x;
  const int total = (NPTS + 1) * 32;
  if (gid >= total) return;
  int n = gid >> 5;
  int c4 = (gid & 31) * 4;
  unsigned short o0, o1, o2, o3;
  if (n < NPTS){
    int b = bidx[n];
    float4 xv = *(const float4*)(x + (size_t)n * CINC + c4);
    float4 sv = *(const float4*)(sn + b * CINC + c4);
    o0 = f2bf(xv.x * sv.x); o1 = f2bf(xv.y * sv.y);
    o2 = f2bf(xv.z * sv.z); o3 = f2bf(xv.w * sv.w);
  } else { o0 = o1 = o2 = o3 = 0; }
  *(ushort4*)(xpad + (size_t)n * CINC + c4) = make_ushort4(o0, o1, o2, o3);
}

__global__ void k_invinit(int* __restrict__ invT){
  int j = blockIdx.x * 256 + threadIdx.x;
  int k = blockIdx.y;
  invT[k * NPTS + j] = NPTS;
}

__global__ void k_invscat(const int* __restrict__ out_idx, const int* __restrict__ in_idx,
                          int* __restrict__ invT){
  int j = blockIdx.x * 256 + threadIdx.x;
  int k = blockIdx.y;
  int o = out_idx[k * NPTS + j];
  if (o < NPTS) invT[k * NPTS + o] = in_idx[k * NPTS + j];
}

// Main conv: identical compute structure to the 169us R8 config (64-pt tile,
// 256 thr, 4 blocks/CU), plus ONE change: XCD-aware chunked block swizzle.
// Mechanism: each xpad row is gathered ~4.4x by output tiles within +-9 tiles
// in sorted order; default dispatch round-robins those neighbors across 8 XCD
// L2s, so every gather misses to loaded L3 (~700cy). Swizzle gives XCD j
// temporally-contiguous 64-tile chunks (resident footprint ~2.6MB < 4MB L2):
// repeat gathers become same-XCD L2 hits (~200cy) and L3 re-fetch dies.
// HW round-robins consecutive blockIdx across XCDs: xcd = bid&7, m = bid>>3;
// tile = ((m>>6)*8 + xcd)*64 + (m&63)  -- bijective on 2048.
__global__ __launch_bounds__(256, 4) void k_conv(
    const unsigned short* __restrict__ xpad,
    const unsigned short* __restrict__ bpack,
    const int* __restrict__ invT,
    const float* __restrict__ dco2,
    const float* __restrict__ cbias,
    const int* __restrict__ bidx,
    float* __restrict__ out){
  __shared__ __align__(16) unsigned short Ash[2 * 64 * 128];  // 32KB double buffer
  int t = threadIdx.x;
  int wave = t >> 6, lane = t & 63;
  int wm = wave >> 1, wn = wave & 1;
  int q = lane >> 4, m16 = lane & 15;
  int bid = blockIdx.x;
  int m = bid >> 3, xcd = bid & 7;
  int tile = ((m >> 6) * 8 + xcd) * 64 + (m & 63);
  int base_pt = tile * 64;

  f32x4 acc[2][4];
  #pragma unroll
  for (int i = 0; i < 2; i++)
    #pragma unroll
    for (int j = 0; j < 4; j++) acc[i][j] = (f32x4){0.f, 0.f, 0.f, 0.f};

  // prefetch tap k into buffer bufsel: source-lane XOR swizzle keeps LDS dest lane-linear
  auto prefetch = [&](int k, int bufsel){
    const int* invk = invT + k * NPTS + base_pt;
    unsigned short* Ab = Ash + bufsel * (64 * 128);
    #pragma unroll
    for (int i = 0; i < 4; i++){
      int chunk = i * 256 + t;              // 1024 chunks = 64 rows x 16
      int row = chunk >> 4, c = chunk & 15;
      int inv = invk[row];
      const unsigned short* src = xpad + (size_t)inv * CINC + ((c ^ row) & 15) * 8;
      GLOAD_LDS16(src, Ab + chunk * 8);
    }
  };

  prefetch(0, 0);
  for (int k = 0; k < K3; k++){
    __syncthreads();                      // drains prefetch(k); releases buf[(k+1)&1]
    if (k + 1 < K3) prefetch(k + 1, (k + 1) & 1);
    const unsigned short* Ab = Ash + (k & 1) * (64 * 128);
    const unsigned short* Bg = bpack + k * 16384;
    #pragma unroll
    for (int kk = 0; kk < 4; kk++){
      int cA = ((kk * 4 + q) ^ m16) & 15;
      bf16x8 a0 = *(const bf16x8*)(Ab + (wm * 32 + m16) * 128 + cA * 8);
      bf16x8 a1 = *(const bf16x8*)(Ab + (wm * 32 + 16 + m16) * 128 + cA * 8);
      #pragma unroll
      for (int jn = 0; jn < 4; jn++){
        bf16x8 b = *(const bf16x8*)(Bg + ((kk * 8 + wn * 4 + jn) * 64 + lane) * 8);
        acc[0][jn] = __builtin_amdgcn_mfma_f32_16x16x32_bf16(a0, b, acc[0][jn], 0, 0, 0);
        acc[1][jn] = __builtin_amdgcn_mfma_f32_16x16x32_bf16(a1, b, acc[1][jn], 0, 0, 0);
      }
    }
  }

  // epilogue: demod + bias + leaky*sqrt2 + clip
  const float S2 = 1.41421356237309515f;
  #pragma unroll
  for (int i = 0; i < 2; i++){
    #pragma unroll
    for (int r = 0; r < 4; r++){
      int row = wm * 32 + i * 16 + q * 4 + r;   // D: row=(lane>>4)*4+reg
      int n = base_pt + row;
      int b = bidx[n];
      const float* dc = dco2 + b * COUTC;
      float* orow = out + (size_t)n * COUTC;
      #pragma unroll
      for (int jn = 0; jn < 4; jn++){
        int col = wn * 64 + jn * 16 + m16;      // D: col=lane&15
        float v = acc[i][jn][r] * dc[col] + cbias[col];
        v = (v < 0.f ? 0.2f * v : v) * S2;
        v = fminf(fmaxf(v, -256.f), 256.f);
        orow[col] = v;
      }
    }
  }
}

extern "C" void kernel_launch(void* const* d_in, const int* in_sizes, int n_in,
                              void* d_out, int out_size, void* d_ws, size_t ws_size,
                              hipStream_t stream){
  const float* x   = (const float*)d_in[0];
  const float* w   = (const float*)d_in[1];
  const float* aw  = (const float*)d_in[2];
  const float* ab  = (const float*)d_in[3];
  const float* cw  = (const float*)d_in[4];
  const float* cb  = (const float*)d_in[5];
  const float* mag = (const float*)d_in[6];
  const int* bidx    = (const int*)d_in[7];
  const int* in_idx  = (const int*)d_in[8];
  const int* out_idx = (const int*)d_in[9];
  float* out = (float*)d_out;
  char* ws = (char*)d_ws;

  float* styles = (float*)(ws + 0);         // 2048 B
  float* sn     = (float*)(ws + 2048);      // 2048 B
  float* wnorm  = (float*)(ws + 4096);      // 512 B
  float* dco2   = (float*)(ws + 4608);      // 2048 B
  float* vmat   = (float*)(ws + 8192);      // 65536 B
  unsigned short* bpack = (unsigned short*)(ws + 73728);    // 884736 B
  unsigned short* xpad  = (unsigned short*)(ws + 958464);   // 33554688 B
  int* invT     = (int*)(ws + 34513152);                    // 14155776 B -> end 48668928

  k_prep_w<<<128, 128, 0, stream>>>(cw, wnorm, vmat, bpack);
  k_styles_dot<<<128, 256, 0, stream>>>(w, aw, ab, styles);
  k_sn_dco<<<64, 512, 0, stream>>>(styles, vmat, wnorm, mag, sn, dco2);
  k_xmod<<<16385, 256, 0, stream>>>(x, sn, bidx, xpad);
  dim3 gi(512, 27);
  k_invinit<<<gi, 256, 0, stream>>>(invT);
  k_invscat<<<gi, 256, 0, stream>>>(out_idx, in_idx, invT);
  k_conv<<<2048, 256, 0, stream>>>(xpad, bpack, invT, dco2, cb, bidx, out);
}